// Round 1
// baseline (16368.411 us; speedup 1.0000x reference)
//
#include <hip/hip_runtime.h>
#include <hip/hip_cooperative_groups.h>
#include <math.h>

namespace cg = cooperative_groups;

// OHNM loss: pos BCE sum + top-k(600000) negative softplus sum, mean over 800000.
//
// R8: collapse 5 post-main kernels into ONE cooperative kernel (2 grid.syncs).
// Theory: R7's 147us >> ~45us of modeled work; the gap is 6 launch/drain
// boundaries + 3 redundant 8MB cand passes. New structure:
//   k_main (2048x256): pos_sum + per-wave cand compaction (unchanged, 0 atomics)
//   k_sel  (coop 64x1024):
//     A: redundant slot-reduce (hard flag) + L1 partial hists from cand (LDS,
//        pure stores)  -> grid.sync
//     B: redundant scan1 -> b1; ONE cand stream: sure-sum + compact b1-keys
//        into per-wave regions (ballot cursors, plain stores)  -> grid.sync
//     C: block 0: gather ~9K b1-keys to LDS (prefix-scan, no atomics),
//        hist2(4096)+hist3(16) in LDS, final combine, write out.
// Anomalies (count shortfall / x>=256 / region or gather overflow) -> correct
// single-block fallback (slow, never taken here).

#define K0 0xBF800000u             // f2key(1.0f)
#define FINE_LIMIT 0xC3800000u     // f2key(256.0f)
#define NWAVES 8192                // k_main: 2048 blocks x 4 waves
#define REG 256                    // cand words per wave (lambda=159, +7.9 sigma)
#define NH1 64                     // k_sel blocks / L1 partial hists
#define SELT 1024                  // k_sel threads per block
#define SELWAVES (NH1 * (SELT / 64))   // 1024 k_sel waves
#define REG2 128                   // b1-key region words per k_sel wave
#define GCAP 8192                  // gather buffer capacity (LDS words)

// ---- ws layout (word offsets) ----
#define CTRL_W   64
#define OFF_H1P  (CTRL_W)                        // 64 x 1024 L1 partials
#define OFF_CNT  (OFF_H1P + NH1 * 1024)          // 8192 per-wave counts
#define OFF_POSP (OFF_CNT + NWAVES)              // 8192 per-wave pos partial (f32)
#define OFF_MAXK (OFF_POSP + NWAVES)             // 8192 per-wave maxkey
#define OFF_SS   (OFF_MAXK + NWAVES)             // 64 per-block sure-sums (f32)
#define OFF_FLG  (OFF_SS + NH1)                  // 1 (+3 pad) overflow flag
#define OFF_CNT2 (OFF_FLG + 4)                   // 1024 per-wave b1 counts
#define OFF_CAND2 (OFF_CNT2 + SELWAVES)          // 1024 x 128 b1-key regions
#define OFF_CAND (OFF_CAND2 + SELWAVES * REG2)   // 16B aligned (222340 % 4 == 0)
#define CANDW    (NWAVES * REG)                  // 2,097,152 words (8 MB)

struct Ctrl { float pos_sum; unsigned cand_count, maxkey, hard; };

__device__ __forceinline__ unsigned f2key(float x) {
    unsigned u = __float_as_uint(x);
    return (u & 0x80000000u) ? ~u : (u | 0x80000000u);
}
__device__ __forceinline__ float key2f(unsigned k) {
    unsigned u = (k & 0x80000000u) ? (k & 0x7FFFFFFFu) : ~k;
    return __uint_as_float(u);
}
__device__ __forceinline__ float softplusf(float x) {
    return fmaxf(x, 0.0f) + __logf(1.0f + __expf(-fabsf(x)));
}
__device__ __forceinline__ float wred(float v) {
    v += __shfl_down(v, 32); v += __shfl_down(v, 16); v += __shfl_down(v, 8);
    v += __shfl_down(v, 4);  v += __shfl_down(v, 2);  v += __shfl_down(v, 1);
    return v;
}
__device__ __forceinline__ unsigned wredmax(unsigned v) {
    v = max(v, (unsigned)__shfl_down((int)v, 32));
    v = max(v, (unsigned)__shfl_down((int)v, 16));
    v = max(v, (unsigned)__shfl_down((int)v, 8));
    v = max(v, (unsigned)__shfl_down((int)v, 4));
    v = max(v, (unsigned)__shfl_down((int)v, 2));
    v = max(v, (unsigned)__shfl_down((int)v, 1));
    return v;
}
// block float-sum; result valid on thread 0
__device__ float bred(float v) {
    __shared__ float sb[16];
    const int lane = threadIdx.x & 63, w = threadIdx.x >> 6;
    const int nw = blockDim.x >> 6;
    v = wred(v);
    if (lane == 0) sb[w] = v;
    __syncthreads();
    float r = 0.0f;
    if (threadIdx.x == 0) for (int i = 0; i < nw; ++i) r += sb[i];
    __syncthreads();
    return r;
}
// block reduce of (sum tot, max mk, or ov, fsum ps); results broadcast to all
__device__ void blockreduce4(unsigned& tot, unsigned& mk, unsigned& ov, float& ps) {
    __shared__ unsigned st[16], sm[16], so[16];
    __shared__ float sf[16];
    __shared__ unsigned rbu[3];
    __shared__ float rbf;
    const int lane = threadIdx.x & 63, w = threadIdx.x >> 6;
    const int nw = blockDim.x >> 6;
    tot += __shfl_down(tot, 32); tot += __shfl_down(tot, 16); tot += __shfl_down(tot, 8);
    tot += __shfl_down(tot, 4);  tot += __shfl_down(tot, 2);  tot += __shfl_down(tot, 1);
    mk = wredmax(mk);
    ov |= (unsigned)__shfl_down((int)ov, 32); ov |= (unsigned)__shfl_down((int)ov, 16);
    ov |= (unsigned)__shfl_down((int)ov, 8);  ov |= (unsigned)__shfl_down((int)ov, 4);
    ov |= (unsigned)__shfl_down((int)ov, 2);  ov |= (unsigned)__shfl_down((int)ov, 1);
    ps = wred(ps);
    if (lane == 0) { st[w] = tot; sm[w] = mk; so[w] = ov; sf[w] = ps; }
    __syncthreads();
    if (threadIdx.x == 0) {
        unsigned T = 0, M = 0, O = 0; float P = 0.0f;
        for (int i = 0; i < nw; ++i) { T += st[i]; M = max(M, sm[i]); O |= so[i]; P += sf[i]; }
        rbu[0] = T; rbu[1] = M; rbu[2] = O; rbf = P;
    }
    __syncthreads();
    tot = rbu[0]; mk = rbu[1]; ov = rbu[2]; ps = rbf;
    __syncthreads();
}

// descending rank-select, summing nparts partial hists; redundant per block.
// All NT threads call. First bin (from top) with cum >= R; r = R - above (>=1).
template<int NT>
__device__ void scan_desc(const unsigned* __restrict__ hist, int nparts,
                          int pstride, int nbins, unsigned R,
                          unsigned* bin_out, unsigned* r_out) {
    __shared__ unsigned sums[NT];
    __shared__ unsigned res[2];
    const int per = nbins / NT;
    const int t = threadIdx.x;
    unsigned local[8];
    unsigned s = 0;
    for (int j = 0; j < per; ++j) {
        const int bin = nbins - 1 - (t * per + j);
        unsigned v = 0;
        for (int p = 0; p < nparts; ++p) v += hist[p * pstride + bin];
        local[j] = v;
        s += v;
    }
    if (t == 0) { res[0] = 0u; res[1] = 1u; }
    sums[t] = s;
    __syncthreads();
    for (int off = 1; off < NT; off <<= 1) {
        unsigned v = (t >= off) ? sums[t - off] : 0u;
        __syncthreads();
        sums[t] += v;
        __syncthreads();
    }
    const unsigned incl = sums[t], excl = incl - s;
    if (excl < R && incl >= R) {
        unsigned cum = excl;
        for (int j = 0; j < per; ++j) {
            if (cum + local[j] >= R) {
                res[0] = (unsigned)(nbins - 1 - (t * per + j));
                res[1] = R - cum;
                break;
            }
            cum += local[j];
        }
    }
    __syncthreads();
    *bin_out = res[0];
    *r_out = res[1];
    __syncthreads();
}

// fine bins: kp = k - K0 (only for k in [K0, FINE_LIMIT))
__device__ __forceinline__ unsigned fl1(unsigned kp) { return kp >> 16; }
__device__ __forceinline__ unsigned fl2(unsigned kp) { return (kp >> 4) & 0xFFFu; }
__device__ __forceinline__ unsigned fl3(unsigned kp) { return kp & 0xFu; }
// hard (coarse) bins: full key range
__device__ __forceinline__ unsigned hl1(unsigned k) { return k >> 22; }
__device__ __forceinline__ unsigned hl2(unsigned k) { return (k >> 10) & 0xFFFu; }
__device__ __forceinline__ unsigned hl3(unsigned k) { return k & 0x3FFu; }

// ---- k_main: pos_sum + per-wave-region compact. ZERO atomics. (unchanged) ----
__global__ __launch_bounds__(256)
void k_main(const float* __restrict__ x, const float* __restrict__ y,
            unsigned* __restrict__ ws, unsigned cap_words, int n) {
    const int tid = threadIdx.x;
    const int lane = tid & 63;
    const unsigned waveid = blockIdx.x * 4 + (tid >> 6);
    unsigned* cand = ws + OFF_CAND;
    const unsigned base = waveid * REG;

    float ps = 0.0f;
    unsigned kmax = 0u, cur = 0u, ovf = 0u;
    const int n4 = n >> 2;
    const float4* x4 = (const float4*)x;
    const float4* y4 = (const float4*)y;
    const unsigned gtid = blockIdx.x * blockDim.x + tid;
    const unsigned gstride = gridDim.x * blockDim.x;
    for (unsigned i = gtid; i < (unsigned)n4; i += gstride) {
        float4 xv = x4[i];
        float4 yv = y4[i];
        float xs[4] = {xv.x, xv.y, xv.z, xv.w};
        float ys[4] = {yv.x, yv.y, yv.z, yv.w};
#pragma unroll
        for (int c = 0; c < 4; ++c) {
            bool pos = ys[c] > 0.0f;
            if (pos) ps += softplusf(-xs[c]);
            unsigned k = f2key(xs[c]);
            bool cnd = (!pos) && (k >= K0);
            unsigned long long mask = __ballot(cnd);
            if (mask) {
                if (cnd) {
                    kmax = max(kmax, k);
                    unsigned slot = cur + (unsigned)__popcll(mask & ((1ull << lane) - 1ull));
                    unsigned gi = base + slot;
                    if (slot < REG && gi < cap_words) cand[gi] = k;
                    else ovf = 1u;
                }
                cur += (unsigned)__popcll(mask);
            }
        }
    }
    // tail (n % 4): wave 0, all lanes (keeps cur uniform)
    if (waveid == 0) {
        for (int i = (n & ~3) + lane; i < n; i += 64) {
            float xs = x[i];
            bool pos = y[i] > 0.0f;
            if (pos) ps += softplusf(-xs);
            unsigned k = f2key(xs);
            bool cnd = (!pos) && (k >= K0);
            unsigned long long mask = __ballot(cnd);
            if (mask) {
                if (cnd) {
                    kmax = max(kmax, k);
                    unsigned slot = cur + (unsigned)__popcll(mask & ((1ull << lane) - 1ull));
                    unsigned gi = base + slot;
                    if (slot < REG && gi < cap_words) cand[gi] = k;
                    else ovf = 1u;
                }
                cur += (unsigned)__popcll(mask);
            }
        }
    }
    // zero-fill padding (stage phases skip k < K0; 0 < K0)
    for (unsigned j = cur + lane; j < REG; j += 64) {
        unsigned gi = base + j;
        if (gi < cap_words) cand[gi] = 0u;
    }
    if (base + REG > cap_words) ovf = 1u;     // region didn't fit
    ps = wred(ps);
    kmax = wredmax(kmax);
    unsigned anyovf = (__ballot(ovf != 0u) != 0ull) ? 0x80000000u : 0u;
    if (lane == 0) {
        ws[OFF_CNT + waveid] = (cur & 0x7FFFFFFFu) | anyovf;
        ((float*)ws)[OFF_POSP + waveid] = ps;
        ws[OFF_MAXK + waveid] = kmax;
    }
}

// ---- correct single-block fallback: coarse 3-level select from x,y ----
// Never taken for the bench input (fine path covers it). Block 0 only.
__device__ void slow_select(const float* __restrict__ x, const float* __restrict__ y,
                            unsigned* __restrict__ ws, int n, unsigned Kneg, int pos,
                            float* __restrict__ out,
                            unsigned* ha /*>=4096*/, unsigned* hb /*>=2048*/) {
    Ctrl* c = (Ctrl*)ws;
    const int t = threadIdx.x;
    __shared__ unsigned bc[2];
    // L1 coarse
    if (t < 1024) ha[t] = 0u;
    __syncthreads();
    for (int i = t; i < n; i += SELT)
        if (y[i] == 0.0f) atomicAdd(&ha[hl1(f2key(x[i]))], 1u);
    __syncthreads();
    if (t == 0) {
        unsigned cum = 0, b = 0, r = 1;
        for (int bin = 1023; bin >= 0; --bin) {
            unsigned v = ha[bin];
            if (cum + v >= Kneg) { b = (unsigned)bin; r = Kneg - cum; break; }
            cum += v;
        }
        bc[0] = b; bc[1] = r;
    }
    __syncthreads();
    const unsigned b1 = bc[0], r1 = bc[1];
    __syncthreads();
    // L2
    for (int i = t; i < 4096; i += SELT) ha[i] = 0u;
    __syncthreads();
    float ss = 0.0f;
    for (int i = t; i < n; i += SELT)
        if (y[i] == 0.0f) {
            unsigned k = f2key(x[i]);
            unsigned b = hl1(k);
            if (b > b1) ss += softplusf(key2f(k));
            else if (b == b1) atomicAdd(&ha[hl2(k)], 1u);
        }
    __syncthreads();
    if (t == 0) {
        unsigned cum = 0, b = 0, r = 1;
        for (int bin = 4095; bin >= 0; --bin) {
            unsigned v = ha[bin];
            if (cum + v >= r1) { b = (unsigned)bin; r = r1 - cum; break; }
            cum += v;
        }
        bc[0] = b; bc[1] = r;
    }
    __syncthreads();
    const unsigned b2 = bc[0], r2 = bc[1];
    // L3
    unsigned* h3c = hb;
    float* h3f = (float*)(hb + 1024);
    if (t < 1024) { h3c[t] = 0u; h3f[t] = 0.0f; }
    __syncthreads();
    float s2 = 0.0f;
    for (int i = t; i < n; i += SELT)
        if (y[i] == 0.0f) {
            unsigned k = f2key(x[i]);
            if (hl1(k) == b1) {
                unsigned l2 = hl2(k);
                if (l2 > b2) s2 += softplusf(key2f(k));
                else if (l2 == b2) {
                    atomicAdd(&h3c[hl3(k)], 1u);
                    atomicAdd(&h3f[hl3(k)], softplusf(key2f(k)));
                }
            }
        }
    __syncthreads();
    ss = bred(ss);
    s2 = bred(s2);
    if (t == 0) {
        unsigned cum = 0, c3 = 0, r3 = 1;
        for (int bin = 1023; bin >= 0; --bin) {
            unsigned v = h3c[bin];
            if (cum + v >= r2) { c3 = (unsigned)bin; r3 = r2 - cum; break; }
            cum += v;
        }
        float sf = 0.0f;
        for (int j = (int)c3 + 1; j < 1024; ++j) sf += h3f[j];
        unsigned H = (b1 << 22) | (b2 << 10) | c3;
        out[0] = (c->pos_sum + ss + s2 + sf + (float)r3 * softplusf(key2f(H)))
                 / (float)(4 * pos);
    }
}

// ---- k_sel: cooperative; phases A/B/C with 2 grid syncs ----
__global__ __launch_bounds__(SELT)
void k_sel(const float* __restrict__ x, const float* __restrict__ y,
           unsigned* __restrict__ ws, const int* __restrict__ pos_num,
           int n, float* __restrict__ out) {
    __shared__ unsigned smA[4096];     // A: L1 hist(1024); C: hist2(4096); slow: h1/h2
    __shared__ unsigned kbuf[GCAP];    // C: gathered b1 keys; slow: h3c+h3f
    __shared__ unsigned psc[SELT];     // C: prefix scan
    __shared__ unsigned h3c[16];
    __shared__ float    h3f[16];
    cg::grid_group grid = cg::this_grid();
    const int t = threadIdx.x;
    const unsigned Kneg = (unsigned)(pos_num[0] * 3);

    // ---- Phase A: redundant slot reduce (hard flag) + L1 partial hists ----
    unsigned tot = 0u, mk = 0u, ov = 0u;
    float psum = 0.0f;
    for (unsigned i = t; i < NWAVES; i += SELT) {
        unsigned cc = ws[OFF_CNT + i];
        tot += cc & 0x7FFFFFFFu;
        ov |= cc >> 31;
        mk = max(mk, ws[OFF_MAXK + i]);
        psum += ((float*)ws)[OFF_POSP + i];
    }
    blockreduce4(tot, mk, ov, psum);
    const bool hard = (tot < Kneg) || (mk >= FINE_LIMIT) || (ov != 0u);
    if (blockIdx.x == 0 && t == 0) {
        Ctrl* c = (Ctrl*)ws;
        c->pos_sum = psum; c->cand_count = tot; c->maxkey = mk; c->hard = hard ? 1u : 0u;
        ws[OFF_FLG] = 0u;
    }
    if (!hard) {
        smA[t] = 0u;                   // zero L1 hist (t < 1024)
        __syncthreads();
        const uint4* c4 = (const uint4*)(ws + OFF_CAND);
        for (unsigned i = blockIdx.x * SELT + t; i < (unsigned)(CANDW / 4); i += NH1 * SELT) {
            uint4 v = c4[i];
            if (v.x >= K0) atomicAdd(&smA[fl1(v.x - K0)], 1u);
            if (v.y >= K0) atomicAdd(&smA[fl1(v.y - K0)], 1u);
            if (v.z >= K0) atomicAdd(&smA[fl1(v.z - K0)], 1u);
            if (v.w >= K0) atomicAdd(&smA[fl1(v.w - K0)], 1u);
        }
        __syncthreads();
        ws[OFF_H1P + blockIdx.x * 1024 + t] = smA[t];   // pure store
    }
    grid.sync();

    // ---- Phase B: scan1 (redundant) + sure-sum + compact b1 keys ----
    unsigned b1 = 0u, r1 = 1u;
    if (!hard) {
        scan_desc<SELT>(ws + OFF_H1P, NH1, 1024, 1024, Kneg, &b1, &r1);
        const unsigned wv = blockIdx.x * (SELT / 64) + (unsigned)(t >> 6);
        const unsigned lane = (unsigned)(t & 63);
        unsigned cur2 = 0u;
        float ssv = 0.0f;
        const uint4* c4 = (const uint4*)(ws + OFF_CAND);
        for (unsigned i = blockIdx.x * SELT + t; i < (unsigned)(CANDW / 4); i += NH1 * SELT) {
            uint4 v = c4[i];
            unsigned ks[4] = {v.x, v.y, v.z, v.w};
#pragma unroll
            for (int cc = 0; cc < 4; ++cc) {
                unsigned k = ks[cc];
                bool ge = (k >= K0);
                unsigned b = ge ? fl1(k - K0) : 0u;
                if (ge && b > b1) ssv += softplusf(key2f(k));
                bool hit = ge && (b == b1);
                unsigned long long m = __ballot(hit);
                if (m) {
                    if (hit) {
                        unsigned slot = cur2 + (unsigned)__popcll(m & ((1ull << lane) - 1ull));
                        if (slot < (unsigned)REG2) ws[OFF_CAND2 + wv * REG2 + slot] = k;
                    }
                    cur2 += (unsigned)__popcll(m);
                }
            }
        }
        if (lane == 0) {
            ws[OFF_CNT2 + wv] = cur2 < (unsigned)REG2 ? cur2 : (unsigned)REG2;
            if (cur2 > (unsigned)REG2) ws[OFF_FLG] = 1u;   // benign same-value race
        }
        ssv = bred(ssv);
        if (t == 0) ((float*)ws)[OFF_SS + blockIdx.x] = ssv;
    }
    grid.sync();

    // ---- Phase C: block 0 finishes everything ----
    if (blockIdx.x != 0) return;
    const int pos = pos_num[0];
    bool slow = hard || (ws[OFF_FLG] != 0u);
    unsigned total = 0u;
    if (!slow) {
        unsigned cnt = ws[OFF_CNT2 + t];
        if (cnt > (unsigned)REG2) cnt = (unsigned)REG2;
        psc[t] = cnt;
        __syncthreads();
        for (int off = 1; off < SELT; off <<= 1) {
            unsigned v = (t >= off) ? psc[t - off] : 0u;
            __syncthreads();
            psc[t] += v;
            __syncthreads();
        }
        total = psc[SELT - 1];
        if (total > (unsigned)GCAP) slow = true;
        else {
            unsigned o0 = psc[t] - cnt;
            for (unsigned j = 0; j < cnt; ++j)
                kbuf[o0 + j] = ws[OFF_CAND2 + (unsigned)t * REG2 + j];
            __syncthreads();
        }
    }
    if (slow) {
        slow_select(x, y, ws, n, Kneg, pos, out, smA, kbuf);
        return;
    }
    // hist2 over gathered keys (all have fl1 == b1)
    for (int i = t; i < 4096; i += SELT) smA[i] = 0u;
    __syncthreads();
    for (unsigned i = t; i < total; i += SELT)
        atomicAdd(&smA[fl2(kbuf[i] - K0)], 1u);
    __syncthreads();
    unsigned b2, r2;
    scan_desc<SELT>(smA, 1, 0, 4096, r1, &b2, &r2);
    if (t < 16) { h3c[t] = 0u; h3f[t] = 0.0f; }
    __syncthreads();
    float s2 = 0.0f;
    for (unsigned i = t; i < total; i += SELT) {
        unsigned k = kbuf[i];
        unsigned l2 = fl2(k - K0);
        if (l2 > b2) s2 += softplusf(key2f(k));
        else if (l2 == b2) {
            atomicAdd(&h3c[fl3(k - K0)], 1u);
            atomicAdd(&h3f[fl3(k - K0)], softplusf(key2f(k)));
        }
    }
    __syncthreads();
    s2 = bred(s2);
    if (t == 0) {
        unsigned cum = 0, c3 = 0, r3 = 1;
        for (int bin = 15; bin >= 0; --bin) {
            unsigned v = h3c[bin];
            if (cum + v >= r2) { c3 = (unsigned)bin; r3 = r2 - cum; break; }
            cum += v;
        }
        float sf = 0.0f;
        for (int j = (int)c3 + 1; j < 16; ++j) sf += h3f[j];
        float ssT = 0.0f;
        for (int i = 0; i < NH1; ++i) ssT += ((float*)ws)[OFF_SS + i];
        Ctrl* c = (Ctrl*)ws;
        unsigned H = K0 + ((b1 << 16) | (b2 << 4) | c3);
        out[0] = (c->pos_sum + ssT + s2 + sf + (float)r3 * softplusf(key2f(H)))
                 / (float)(4 * pos);
    }
}

extern "C" void kernel_launch(void* const* d_in, const int* in_sizes, int n_in,
                              void* d_out, int out_size, void* d_ws, size_t ws_size,
                              hipStream_t stream) {
    const float* x = (const float*)d_in[0];
    const float* y = (const float*)d_in[1];
    const int* pos_num = (const int*)d_in[2];
    float* out = (float*)d_out;
    const int n = in_sizes[0];

    unsigned* ws = (unsigned*)d_ws;
    unsigned cap_words = 0u;
    if (ws_size / 4 > (size_t)OFF_CAND)
        cap_words = (unsigned)(ws_size / 4 - OFF_CAND);
    if (cap_words > (unsigned)CANDW) cap_words = (unsigned)CANDW;

    k_main<<<2048, 256, 0, stream>>>(x, y, ws, cap_words, n);

    void* kargs[] = { (void*)&x, (void*)&y, (void*)&ws, (void*)&pos_num,
                      (void*)&n, (void*)&out };
    hipLaunchCooperativeKernel(k_sel, dim3(NH1), dim3(SELT), kargs, 0, stream);
}

// Round 2
// 169.172 us; speedup vs baseline: 96.7558x; 96.7558x over previous
//
#include <hip/hip_runtime.h>
#include <hip/hip_cooperative_groups.h>
#include <math.h>

namespace cg = cooperative_groups;

// OHNM loss: pos BCE sum + top-k(600000) negative softplus sum, mean over 800000.
//
// R9: R8's cooperative structure, minus the GCAP bug. R8 post-mortem: the
// b1-bin holds ~8.9K keys but the LDS gather cap was 8192 -> phase C took the
// single-block slow fallback every run (104MB fetch @ 6.5 GB/s = one-CU
// latency-bound streaming, 16ms). Fix: NO LDS gather. Phase C builds
// hist2/hist3 by reading the per-wave b1-key regions straight from global
// (9K L2-hot words, read twice). Overflow now only depends on REG2=128 per
// k_sel wave (mean 8.7 keys -> astronomically safe); correct slow fallback
// kept for true anomalies (count shortfall / x>=256 / region overflow).
//   k_main (2048x256): pos_sum + per-wave cand compaction (0 atomics)
//   k_sel  (coop 64x1024):
//     A: redundant slot-reduce (hard flag) + L1 partial hists from cand (LDS,
//        pure stores)  -> grid.sync
//     B: redundant scan1 -> b1; ONE cand stream: sure-sum + compact b1-keys
//        into per-wave regions (ballot cursors, plain stores)  -> grid.sync
//     C: block 0: hist2(4096 LDS) from global regions, scan2, s2 + hist3(16),
//        scan3, final combine, write out.

#define K0 0xBF800000u             // f2key(1.0f)
#define FINE_LIMIT 0xC3800000u     // f2key(256.0f)
#define NWAVES 8192                // k_main: 2048 blocks x 4 waves
#define REG 256                    // cand words per wave (lambda=159, +7.9 sigma)
#define NH1 64                     // k_sel blocks / L1 partial hists
#define SELT 1024                  // k_sel threads per block
#define SELWAVES (NH1 * (SELT / 64))   // 1024 k_sel waves
#define REG2 128                   // b1-key region words per k_sel wave (mean ~8.7)

// ---- ws layout (word offsets) ----
#define CTRL_W   64
#define OFF_H1P  (CTRL_W)                        // 64 x 1024 L1 partials
#define OFF_CNT  (OFF_H1P + NH1 * 1024)          // 8192 per-wave counts
#define OFF_POSP (OFF_CNT + NWAVES)              // 8192 per-wave pos partial (f32)
#define OFF_MAXK (OFF_POSP + NWAVES)             // 8192 per-wave maxkey
#define OFF_SS   (OFF_MAXK + NWAVES)             // 64 per-block sure-sums (f32)
#define OFF_FLG  (OFF_SS + NH1)                  // 1 (+3 pad) overflow flag
#define OFF_CNT2 (OFF_FLG + 4)                   // 1024 per-wave b1 counts
#define OFF_CAND2 (OFF_CNT2 + SELWAVES)          // 1024 x 128 b1-key regions
#define OFF_CAND (OFF_CAND2 + SELWAVES * REG2)   // 16B aligned (222340 % 4 == 0)
#define CANDW    (NWAVES * REG)                  // 2,097,152 words (8 MB)

struct Ctrl { float pos_sum; unsigned cand_count, maxkey, hard; };

__device__ __forceinline__ unsigned f2key(float x) {
    unsigned u = __float_as_uint(x);
    return (u & 0x80000000u) ? ~u : (u | 0x80000000u);
}
__device__ __forceinline__ float key2f(unsigned k) {
    unsigned u = (k & 0x80000000u) ? (k & 0x7FFFFFFFu) : ~k;
    return __uint_as_float(u);
}
__device__ __forceinline__ float softplusf(float x) {
    return fmaxf(x, 0.0f) + __logf(1.0f + __expf(-fabsf(x)));
}
__device__ __forceinline__ float wred(float v) {
    v += __shfl_down(v, 32); v += __shfl_down(v, 16); v += __shfl_down(v, 8);
    v += __shfl_down(v, 4);  v += __shfl_down(v, 2);  v += __shfl_down(v, 1);
    return v;
}
__device__ __forceinline__ unsigned wredmax(unsigned v) {
    v = max(v, (unsigned)__shfl_down((int)v, 32));
    v = max(v, (unsigned)__shfl_down((int)v, 16));
    v = max(v, (unsigned)__shfl_down((int)v, 8));
    v = max(v, (unsigned)__shfl_down((int)v, 4));
    v = max(v, (unsigned)__shfl_down((int)v, 2));
    v = max(v, (unsigned)__shfl_down((int)v, 1));
    return v;
}
// block float-sum; result valid on thread 0
__device__ float bred(float v) {
    __shared__ float sb[16];
    const int lane = threadIdx.x & 63, w = threadIdx.x >> 6;
    const int nw = blockDim.x >> 6;
    v = wred(v);
    if (lane == 0) sb[w] = v;
    __syncthreads();
    float r = 0.0f;
    if (threadIdx.x == 0) for (int i = 0; i < nw; ++i) r += sb[i];
    __syncthreads();
    return r;
}
// block reduce of (sum tot, max mk, or ov, fsum ps); results broadcast to all
__device__ void blockreduce4(unsigned& tot, unsigned& mk, unsigned& ov, float& ps) {
    __shared__ unsigned st[16], sm[16], so[16];
    __shared__ float sf[16];
    __shared__ unsigned rbu[3];
    __shared__ float rbf;
    const int lane = threadIdx.x & 63, w = threadIdx.x >> 6;
    const int nw = blockDim.x >> 6;
    tot += __shfl_down(tot, 32); tot += __shfl_down(tot, 16); tot += __shfl_down(tot, 8);
    tot += __shfl_down(tot, 4);  tot += __shfl_down(tot, 2);  tot += __shfl_down(tot, 1);
    mk = wredmax(mk);
    ov |= (unsigned)__shfl_down((int)ov, 32); ov |= (unsigned)__shfl_down((int)ov, 16);
    ov |= (unsigned)__shfl_down((int)ov, 8);  ov |= (unsigned)__shfl_down((int)ov, 4);
    ov |= (unsigned)__shfl_down((int)ov, 2);  ov |= (unsigned)__shfl_down((int)ov, 1);
    ps = wred(ps);
    if (lane == 0) { st[w] = tot; sm[w] = mk; so[w] = ov; sf[w] = ps; }
    __syncthreads();
    if (threadIdx.x == 0) {
        unsigned T = 0, M = 0, O = 0; float P = 0.0f;
        for (int i = 0; i < nw; ++i) { T += st[i]; M = max(M, sm[i]); O |= so[i]; P += sf[i]; }
        rbu[0] = T; rbu[1] = M; rbu[2] = O; rbf = P;
    }
    __syncthreads();
    tot = rbu[0]; mk = rbu[1]; ov = rbu[2]; ps = rbf;
    __syncthreads();
}

// descending rank-select, summing nparts partial hists; redundant per block.
// All NT threads call. First bin (from top) with cum >= R; r = R - above (>=1).
template<int NT>
__device__ void scan_desc(const unsigned* __restrict__ hist, int nparts,
                          int pstride, int nbins, unsigned R,
                          unsigned* bin_out, unsigned* r_out) {
    __shared__ unsigned sums[NT];
    __shared__ unsigned res[2];
    const int per = nbins / NT;
    const int t = threadIdx.x;
    unsigned local[8];
    unsigned s = 0;
    for (int j = 0; j < per; ++j) {
        const int bin = nbins - 1 - (t * per + j);
        unsigned v = 0;
        for (int p = 0; p < nparts; ++p) v += hist[p * pstride + bin];
        local[j] = v;
        s += v;
    }
    if (t == 0) { res[0] = 0u; res[1] = 1u; }
    sums[t] = s;
    __syncthreads();
    for (int off = 1; off < NT; off <<= 1) {
        unsigned v = (t >= off) ? sums[t - off] : 0u;
        __syncthreads();
        sums[t] += v;
        __syncthreads();
    }
    const unsigned incl = sums[t], excl = incl - s;
    if (excl < R && incl >= R) {
        unsigned cum = excl;
        for (int j = 0; j < per; ++j) {
            if (cum + local[j] >= R) {
                res[0] = (unsigned)(nbins - 1 - (t * per + j));
                res[1] = R - cum;
                break;
            }
            cum += local[j];
        }
    }
    __syncthreads();
    *bin_out = res[0];
    *r_out = res[1];
    __syncthreads();
}

// fine bins: kp = k - K0 (only for k in [K0, FINE_LIMIT))
__device__ __forceinline__ unsigned fl1(unsigned kp) { return kp >> 16; }
__device__ __forceinline__ unsigned fl2(unsigned kp) { return (kp >> 4) & 0xFFFu; }
__device__ __forceinline__ unsigned fl3(unsigned kp) { return kp & 0xFu; }
// hard (coarse) bins: full key range
__device__ __forceinline__ unsigned hl1(unsigned k) { return k >> 22; }
__device__ __forceinline__ unsigned hl2(unsigned k) { return (k >> 10) & 0xFFFu; }
__device__ __forceinline__ unsigned hl3(unsigned k) { return k & 0x3FFu; }

// ---- k_main: pos_sum + per-wave-region compact. ZERO atomics. (unchanged) ----
__global__ __launch_bounds__(256)
void k_main(const float* __restrict__ x, const float* __restrict__ y,
            unsigned* __restrict__ ws, unsigned cap_words, int n) {
    const int tid = threadIdx.x;
    const int lane = tid & 63;
    const unsigned waveid = blockIdx.x * 4 + (tid >> 6);
    unsigned* cand = ws + OFF_CAND;
    const unsigned base = waveid * REG;

    float ps = 0.0f;
    unsigned kmax = 0u, cur = 0u, ovf = 0u;
    const int n4 = n >> 2;
    const float4* x4 = (const float4*)x;
    const float4* y4 = (const float4*)y;
    const unsigned gtid = blockIdx.x * blockDim.x + tid;
    const unsigned gstride = gridDim.x * blockDim.x;
    for (unsigned i = gtid; i < (unsigned)n4; i += gstride) {
        float4 xv = x4[i];
        float4 yv = y4[i];
        float xs[4] = {xv.x, xv.y, xv.z, xv.w};
        float ys[4] = {yv.x, yv.y, yv.z, yv.w};
#pragma unroll
        for (int c = 0; c < 4; ++c) {
            bool pos = ys[c] > 0.0f;
            if (pos) ps += softplusf(-xs[c]);
            unsigned k = f2key(xs[c]);
            bool cnd = (!pos) && (k >= K0);
            unsigned long long mask = __ballot(cnd);
            if (mask) {
                if (cnd) {
                    kmax = max(kmax, k);
                    unsigned slot = cur + (unsigned)__popcll(mask & ((1ull << lane) - 1ull));
                    unsigned gi = base + slot;
                    if (slot < REG && gi < cap_words) cand[gi] = k;
                    else ovf = 1u;
                }
                cur += (unsigned)__popcll(mask);
            }
        }
    }
    // tail (n % 4): wave 0, all lanes (keeps cur uniform)
    if (waveid == 0) {
        for (int i = (n & ~3) + lane; i < n; i += 64) {
            float xs = x[i];
            bool pos = y[i] > 0.0f;
            if (pos) ps += softplusf(-xs);
            unsigned k = f2key(xs);
            bool cnd = (!pos) && (k >= K0);
            unsigned long long mask = __ballot(cnd);
            if (mask) {
                if (cnd) {
                    kmax = max(kmax, k);
                    unsigned slot = cur + (unsigned)__popcll(mask & ((1ull << lane) - 1ull));
                    unsigned gi = base + slot;
                    if (slot < REG && gi < cap_words) cand[gi] = k;
                    else ovf = 1u;
                }
                cur += (unsigned)__popcll(mask);
            }
        }
    }
    // zero-fill padding (stage phases skip k < K0; 0 < K0)
    for (unsigned j = cur + lane; j < REG; j += 64) {
        unsigned gi = base + j;
        if (gi < cap_words) cand[gi] = 0u;
    }
    if (base + REG > cap_words) ovf = 1u;     // region didn't fit
    ps = wred(ps);
    kmax = wredmax(kmax);
    unsigned anyovf = (__ballot(ovf != 0u) != 0ull) ? 0x80000000u : 0u;
    if (lane == 0) {
        ws[OFF_CNT + waveid] = (cur & 0x7FFFFFFFu) | anyovf;
        ((float*)ws)[OFF_POSP + waveid] = ps;
        ws[OFF_MAXK + waveid] = kmax;
    }
}

// ---- correct single-block fallback: coarse 3-level select from x,y ----
// Never taken for the bench input (fine path covers it). Block 0 only.
__device__ void slow_select(const float* __restrict__ x, const float* __restrict__ y,
                            unsigned* __restrict__ ws, int n, unsigned Kneg, int pos,
                            float* __restrict__ out,
                            unsigned* ha /*>=4096*/, unsigned* hb /*>=2048*/) {
    Ctrl* c = (Ctrl*)ws;
    const int t = threadIdx.x;
    __shared__ unsigned bc[2];
    // L1 coarse
    if (t < 1024) ha[t] = 0u;
    __syncthreads();
    for (int i = t; i < n; i += SELT)
        if (y[i] == 0.0f) atomicAdd(&ha[hl1(f2key(x[i]))], 1u);
    __syncthreads();
    if (t == 0) {
        unsigned cum = 0, b = 0, r = 1;
        for (int bin = 1023; bin >= 0; --bin) {
            unsigned v = ha[bin];
            if (cum + v >= Kneg) { b = (unsigned)bin; r = Kneg - cum; break; }
            cum += v;
        }
        bc[0] = b; bc[1] = r;
    }
    __syncthreads();
    const unsigned b1 = bc[0], r1 = bc[1];
    __syncthreads();
    // L2
    for (int i = t; i < 4096; i += SELT) ha[i] = 0u;
    __syncthreads();
    float ss = 0.0f;
    for (int i = t; i < n; i += SELT)
        if (y[i] == 0.0f) {
            unsigned k = f2key(x[i]);
            unsigned b = hl1(k);
            if (b > b1) ss += softplusf(key2f(k));
            else if (b == b1) atomicAdd(&ha[hl2(k)], 1u);
        }
    __syncthreads();
    if (t == 0) {
        unsigned cum = 0, b = 0, r = 1;
        for (int bin = 4095; bin >= 0; --bin) {
            unsigned v = ha[bin];
            if (cum + v >= r1) { b = (unsigned)bin; r = r1 - cum; break; }
            cum += v;
        }
        bc[0] = b; bc[1] = r;
    }
    __syncthreads();
    const unsigned b2 = bc[0], r2 = bc[1];
    // L3
    unsigned* h3c = hb;
    float* h3f = (float*)(hb + 1024);
    if (t < 1024) { h3c[t] = 0u; h3f[t] = 0.0f; }
    __syncthreads();
    float s2 = 0.0f;
    for (int i = t; i < n; i += SELT)
        if (y[i] == 0.0f) {
            unsigned k = f2key(x[i]);
            if (hl1(k) == b1) {
                unsigned l2 = hl2(k);
                if (l2 > b2) s2 += softplusf(key2f(k));
                else if (l2 == b2) {
                    atomicAdd(&h3c[hl3(k)], 1u);
                    atomicAdd(&h3f[hl3(k)], softplusf(key2f(k)));
                }
            }
        }
    __syncthreads();
    ss = bred(ss);
    s2 = bred(s2);
    if (t == 0) {
        unsigned cum = 0, c3 = 0, r3 = 1;
        for (int bin = 1023; bin >= 0; --bin) {
            unsigned v = h3c[bin];
            if (cum + v >= r2) { c3 = (unsigned)bin; r3 = r2 - cum; break; }
            cum += v;
        }
        float sf = 0.0f;
        for (int j = (int)c3 + 1; j < 1024; ++j) sf += h3f[j];
        unsigned H = (b1 << 22) | (b2 << 10) | c3;
        out[0] = (c->pos_sum + ss + s2 + sf + (float)r3 * softplusf(key2f(H)))
                 / (float)(4 * pos);
    }
}

// ---- k_sel: cooperative; phases A/B/C with 2 grid syncs ----
__global__ __launch_bounds__(SELT)
void k_sel(const float* __restrict__ x, const float* __restrict__ y,
           unsigned* __restrict__ ws, const int* __restrict__ pos_num,
           int n, float* __restrict__ out) {
    __shared__ unsigned smA[4096];     // A: L1 hist(1024); C: hist2(4096); slow: h1/h2
    __shared__ unsigned slowbuf[2048]; // slow: h3c+h3f
    __shared__ unsigned h3c[16];
    __shared__ float    h3f[16];
    cg::grid_group grid = cg::this_grid();
    const int t = threadIdx.x;
    const unsigned Kneg = (unsigned)(pos_num[0] * 3);

    // ---- Phase A: redundant slot reduce (hard flag) + L1 partial hists ----
    unsigned tot = 0u, mk = 0u, ov = 0u;
    float psum = 0.0f;
    for (unsigned i = t; i < NWAVES; i += SELT) {
        unsigned cc = ws[OFF_CNT + i];
        tot += cc & 0x7FFFFFFFu;
        ov |= cc >> 31;
        mk = max(mk, ws[OFF_MAXK + i]);
        psum += ((float*)ws)[OFF_POSP + i];
    }
    blockreduce4(tot, mk, ov, psum);
    const bool hard = (tot < Kneg) || (mk >= FINE_LIMIT) || (ov != 0u);
    if (blockIdx.x == 0 && t == 0) {
        Ctrl* c = (Ctrl*)ws;
        c->pos_sum = psum; c->cand_count = tot; c->maxkey = mk; c->hard = hard ? 1u : 0u;
        ws[OFF_FLG] = 0u;
    }
    if (!hard) {
        smA[t] = 0u;                   // zero L1 hist (t < 1024)
        __syncthreads();
        const uint4* c4 = (const uint4*)(ws + OFF_CAND);
        for (unsigned i = blockIdx.x * SELT + t; i < (unsigned)(CANDW / 4); i += NH1 * SELT) {
            uint4 v = c4[i];
            if (v.x >= K0) atomicAdd(&smA[fl1(v.x - K0)], 1u);
            if (v.y >= K0) atomicAdd(&smA[fl1(v.y - K0)], 1u);
            if (v.z >= K0) atomicAdd(&smA[fl1(v.z - K0)], 1u);
            if (v.w >= K0) atomicAdd(&smA[fl1(v.w - K0)], 1u);
        }
        __syncthreads();
        ws[OFF_H1P + blockIdx.x * 1024 + t] = smA[t];   // pure store
    }
    grid.sync();

    // ---- Phase B: scan1 (redundant) + sure-sum + compact b1 keys ----
    unsigned b1 = 0u, r1 = 1u;
    if (!hard) {
        scan_desc<SELT>(ws + OFF_H1P, NH1, 1024, 1024, Kneg, &b1, &r1);
        const unsigned wv = blockIdx.x * (SELT / 64) + (unsigned)(t >> 6);
        const unsigned lane = (unsigned)(t & 63);
        unsigned cur2 = 0u;
        float ssv = 0.0f;
        const uint4* c4 = (const uint4*)(ws + OFF_CAND);
        for (unsigned i = blockIdx.x * SELT + t; i < (unsigned)(CANDW / 4); i += NH1 * SELT) {
            uint4 v = c4[i];
            unsigned ks[4] = {v.x, v.y, v.z, v.w};
#pragma unroll
            for (int cc = 0; cc < 4; ++cc) {
                unsigned k = ks[cc];
                bool ge = (k >= K0);
                unsigned b = ge ? fl1(k - K0) : 0u;
                if (ge && b > b1) ssv += softplusf(key2f(k));
                bool hit = ge && (b == b1);
                unsigned long long m = __ballot(hit);
                if (m) {
                    if (hit) {
                        unsigned slot = cur2 + (unsigned)__popcll(m & ((1ull << lane) - 1ull));
                        if (slot < (unsigned)REG2) ws[OFF_CAND2 + wv * REG2 + slot] = k;
                    }
                    cur2 += (unsigned)__popcll(m);
                }
            }
        }
        if (lane == 0) {
            ws[OFF_CNT2 + wv] = cur2 < (unsigned)REG2 ? cur2 : (unsigned)REG2;
            if (cur2 > (unsigned)REG2) ws[OFF_FLG] = 1u;   // benign same-value race
        }
        ssv = bred(ssv);
        if (t == 0) ((float*)ws)[OFF_SS + blockIdx.x] = ssv;
    }
    grid.sync();

    // ---- Phase C: block 0 finishes everything (no LDS gather; global regions) ----
    if (blockIdx.x != 0) return;
    const int pos = pos_num[0];
    const bool slow = hard || (ws[OFF_FLG] != 0u);
    if (slow) {
        slow_select(x, y, ws, n, Kneg, pos, out, smA, slowbuf);
        return;
    }
    // hist2 over b1-keys read from per-wave global regions (thread t = region t)
    for (int i = t; i < 4096; i += SELT) smA[i] = 0u;
    __syncthreads();
    const unsigned cnt = ws[OFF_CNT2 + t];           // already clamped <= REG2
    const unsigned rbase = OFF_CAND2 + (unsigned)t * REG2;
    for (unsigned j = 0; j < cnt; ++j)
        atomicAdd(&smA[fl2(ws[rbase + j] - K0)], 1u);
    __syncthreads();
    unsigned b2, r2;
    scan_desc<SELT>(smA, 1, 0, 4096, r1, &b2, &r2);
    if (t < 16) { h3c[t] = 0u; h3f[t] = 0.0f; }
    __syncthreads();
    float s2 = 0.0f;
    for (unsigned j = 0; j < cnt; ++j) {
        unsigned k = ws[rbase + j];
        unsigned l2 = fl2(k - K0);
        if (l2 > b2) s2 += softplusf(key2f(k));
        else if (l2 == b2) {
            atomicAdd(&h3c[fl3(k - K0)], 1u);
            atomicAdd(&h3f[fl3(k - K0)], softplusf(key2f(k)));
        }
    }
    __syncthreads();
    s2 = bred(s2);
    if (t == 0) {
        unsigned cum = 0, c3 = 0, r3 = 1;
        for (int bin = 15; bin >= 0; --bin) {
            unsigned v = h3c[bin];
            if (cum + v >= r2) { c3 = (unsigned)bin; r3 = r2 - cum; break; }
            cum += v;
        }
        float sf = 0.0f;
        for (int j = (int)c3 + 1; j < 16; ++j) sf += h3f[j];
        float ssT = 0.0f;
        for (int i = 0; i < NH1; ++i) ssT += ((float*)ws)[OFF_SS + i];
        Ctrl* c = (Ctrl*)ws;
        unsigned H = K0 + ((b1 << 16) | (b2 << 4) | c3);
        out[0] = (c->pos_sum + ssT + s2 + sf + (float)r3 * softplusf(key2f(H)))
                 / (float)(4 * pos);
    }
}

extern "C" void kernel_launch(void* const* d_in, const int* in_sizes, int n_in,
                              void* d_out, int out_size, void* d_ws, size_t ws_size,
                              hipStream_t stream) {
    const float* x = (const float*)d_in[0];
    const float* y = (const float*)d_in[1];
    const int* pos_num = (const int*)d_in[2];
    float* out = (float*)d_out;
    const int n = in_sizes[0];

    unsigned* ws = (unsigned*)d_ws;
    unsigned cap_words = 0u;
    if (ws_size / 4 > (size_t)OFF_CAND)
        cap_words = (unsigned)(ws_size / 4 - OFF_CAND);
    if (cap_words > (unsigned)CANDW) cap_words = (unsigned)CANDW;

    k_main<<<2048, 256, 0, stream>>>(x, y, ws, cap_words, n);

    void* kargs[] = { (void*)&x, (void*)&y, (void*)&ws, (void*)&pos_num,
                      (void*)&n, (void*)&out };
    hipLaunchCooperativeKernel(k_sel, dim3(NH1), dim3(SELT), kargs, 0, stream);
}

// Round 3
// 139.576 us; speedup vs baseline: 117.2725x; 1.2120x over previous
//
#include <hip/hip_runtime.h>
#include <math.h>

// OHNM loss: pos BCE sum + top-k(600000) negative softplus sum, mean over 800000.
//
// R10: no cooperative launch (R9 post-mortem: coop submission overhead ~80us).
// Grid syncs -> kernel boundaries; L1 histogram folded INTO k_main (per-block
// LDS hist + sparse atomic merge into 16 pre-zeroed global partials), so the
// cand array is streamed only ONCE after k_main.
//   memset(64KB):  zero CTRL + 16x1024 L1 partials (ws is poisoned)
//   k_main (2048x256): pos_sum + per-wave cand compact + LDS L1 hist ->
//                      atomic merge (only nonzero bins, ~200K atomics total)
//   k_B    (256x256):  slot-reduce (hard flag, redundant/block), scan1 from
//                      16 partials (redundant), ONE cand stream: sure-sum +
//                      b1-key compaction into per-wave regions (ballot
//                      cursors, plain stores)
//   k_C    (1x1024):   hist2(4096 LDS) from the ~9K compacted keys, scan2,
//                      s2 + hist3(16), scan3, final combine -> out
// Anomalies (count shortfall / x>=256 / region overflow) -> correct
// single-block slow fallback in k_C (never taken for this input).

#define K0 0xBF800000u             // f2key(1.0f)
#define FINE_LIMIT 0xC3800000u     // f2key(256.0f)
#define NWAVES 8192                // k_main: 2048 blocks x 4 waves
#define REG 256                    // cand words per wave (lambda=159, +7.9 sigma)
#define NPART 16                   // L1 partial hists (merged by k_main atomics)
#define BBLK 256                   // k_B blocks
#define BT   256                   // k_B threads
#define SELWAVES (BBLK * (BT / 64))    // 1024 k_B waves
#define REG2 128                   // b1-key region words per k_B wave (mean ~8.7)
#define SELT 1024                  // k_C threads

// ---- ws layout (word offsets) ----
#define OFF_FLG  8                               // inside CTRL area (pre-zeroed)
#define OFF_H1P  64                              // 16 x 1024 L1 partials (pre-zeroed)
#define OFF_CNT  (OFF_H1P + NPART * 1024)        // 8192 per-wave counts
#define OFF_POSP (OFF_CNT + NWAVES)              // 8192 per-wave pos partial (f32)
#define OFF_MAXK (OFF_POSP + NWAVES)             // 8192 per-wave maxkey
#define OFF_SS   (OFF_MAXK + NWAVES)             // 256 per-block sure-sums (f32)
#define OFF_CNT2 (OFF_SS + BBLK)                 // 1024 per-wave b1 counts
#define OFF_CAND2 (OFF_CNT2 + SELWAVES)          // 1024 x 128 b1-key regions
#define OFF_CAND (OFF_CAND2 + SELWAVES * REG2)   // 173376 (16B aligned)
#define CANDW    (NWAVES * REG)                  // 2,097,152 words (8 MB)
#define ZERO_BYTES (OFF_CNT * 4)                 // CTRL + partials = 65792 B

struct Ctrl { float pos_sum; unsigned cand_count, maxkey, hard; };

__device__ __forceinline__ unsigned f2key(float x) {
    unsigned u = __float_as_uint(x);
    return (u & 0x80000000u) ? ~u : (u | 0x80000000u);
}
__device__ __forceinline__ float key2f(unsigned k) {
    unsigned u = (k & 0x80000000u) ? (k & 0x7FFFFFFFu) : ~k;
    return __uint_as_float(u);
}
__device__ __forceinline__ float softplusf(float x) {
    return fmaxf(x, 0.0f) + __logf(1.0f + __expf(-fabsf(x)));
}
__device__ __forceinline__ float wred(float v) {
    v += __shfl_down(v, 32); v += __shfl_down(v, 16); v += __shfl_down(v, 8);
    v += __shfl_down(v, 4);  v += __shfl_down(v, 2);  v += __shfl_down(v, 1);
    return v;
}
__device__ __forceinline__ unsigned wredmax(unsigned v) {
    v = max(v, (unsigned)__shfl_down((int)v, 32));
    v = max(v, (unsigned)__shfl_down((int)v, 16));
    v = max(v, (unsigned)__shfl_down((int)v, 8));
    v = max(v, (unsigned)__shfl_down((int)v, 4));
    v = max(v, (unsigned)__shfl_down((int)v, 2));
    v = max(v, (unsigned)__shfl_down((int)v, 1));
    return v;
}
// block float-sum; result valid on thread 0
__device__ float bred(float v) {
    __shared__ float sb[16];
    const int lane = threadIdx.x & 63, w = threadIdx.x >> 6;
    const int nw = blockDim.x >> 6;
    v = wred(v);
    if (lane == 0) sb[w] = v;
    __syncthreads();
    float r = 0.0f;
    if (threadIdx.x == 0) for (int i = 0; i < nw; ++i) r += sb[i];
    __syncthreads();
    return r;
}
// block reduce of (sum tot, max mk, or ov, fsum ps); results broadcast to all
__device__ void blockreduce4(unsigned& tot, unsigned& mk, unsigned& ov, float& ps) {
    __shared__ unsigned st[16], sm[16], so[16];
    __shared__ float sf[16];
    __shared__ unsigned rbu[3];
    __shared__ float rbf;
    const int lane = threadIdx.x & 63, w = threadIdx.x >> 6;
    const int nw = blockDim.x >> 6;
    tot += __shfl_down(tot, 32); tot += __shfl_down(tot, 16); tot += __shfl_down(tot, 8);
    tot += __shfl_down(tot, 4);  tot += __shfl_down(tot, 2);  tot += __shfl_down(tot, 1);
    mk = wredmax(mk);
    ov |= (unsigned)__shfl_down((int)ov, 32); ov |= (unsigned)__shfl_down((int)ov, 16);
    ov |= (unsigned)__shfl_down((int)ov, 8);  ov |= (unsigned)__shfl_down((int)ov, 4);
    ov |= (unsigned)__shfl_down((int)ov, 2);  ov |= (unsigned)__shfl_down((int)ov, 1);
    ps = wred(ps);
    if (lane == 0) { st[w] = tot; sm[w] = mk; so[w] = ov; sf[w] = ps; }
    __syncthreads();
    if (threadIdx.x == 0) {
        unsigned T = 0, M = 0, O = 0; float P = 0.0f;
        for (int i = 0; i < nw; ++i) { T += st[i]; M = max(M, sm[i]); O |= so[i]; P += sf[i]; }
        rbu[0] = T; rbu[1] = M; rbu[2] = O; rbf = P;
    }
    __syncthreads();
    tot = rbu[0]; mk = rbu[1]; ov = rbu[2]; ps = rbf;
    __syncthreads();
}

// descending rank-select, summing nparts partial hists; redundant per block.
// All NT threads call. First bin (from top) with cum >= R; r = R - above (>=1).
template<int NT>
__device__ void scan_desc(const unsigned* __restrict__ hist, int nparts,
                          int pstride, int nbins, unsigned R,
                          unsigned* bin_out, unsigned* r_out) {
    __shared__ unsigned sums[NT];
    __shared__ unsigned res[2];
    const int per = nbins / NT;
    const int t = threadIdx.x;
    unsigned local[8];
    unsigned s = 0;
    for (int j = 0; j < per; ++j) {
        const int bin = nbins - 1 - (t * per + j);
        unsigned v = 0;
        for (int p = 0; p < nparts; ++p) v += hist[p * pstride + bin];
        local[j] = v;
        s += v;
    }
    if (t == 0) { res[0] = 0u; res[1] = 1u; }
    sums[t] = s;
    __syncthreads();
    for (int off = 1; off < NT; off <<= 1) {
        unsigned v = (t >= off) ? sums[t - off] : 0u;
        __syncthreads();
        sums[t] += v;
        __syncthreads();
    }
    const unsigned incl = sums[t], excl = incl - s;
    if (excl < R && incl >= R) {
        unsigned cum = excl;
        for (int j = 0; j < per; ++j) {
            if (cum + local[j] >= R) {
                res[0] = (unsigned)(nbins - 1 - (t * per + j));
                res[1] = R - cum;
                break;
            }
            cum += local[j];
        }
    }
    __syncthreads();
    *bin_out = res[0];
    *r_out = res[1];
    __syncthreads();
}

// fine bins: kp = k - K0 (only for k in [K0, FINE_LIMIT))
__device__ __forceinline__ unsigned fl1(unsigned kp) { return kp >> 16; }
__device__ __forceinline__ unsigned fl2(unsigned kp) { return (kp >> 4) & 0xFFFu; }
__device__ __forceinline__ unsigned fl3(unsigned kp) { return kp & 0xFu; }
// hard (coarse) bins: full key range
__device__ __forceinline__ unsigned hl1(unsigned k) { return k >> 22; }
__device__ __forceinline__ unsigned hl2(unsigned k) { return (k >> 10) & 0xFFFu; }
__device__ __forceinline__ unsigned hl3(unsigned k) { return k & 0x3FFu; }

// ---- k_main: pos_sum + per-wave compact + LDS L1 hist -> partial merge ----
__global__ __launch_bounds__(256)
void k_main(const float* __restrict__ x, const float* __restrict__ y,
            unsigned* __restrict__ ws, unsigned cap_words, int n) {
    __shared__ unsigned h[1024];
    const int tid = threadIdx.x;
    const int lane = tid & 63;
    const unsigned waveid = blockIdx.x * 4 + (tid >> 6);
    unsigned* cand = ws + OFF_CAND;
    const unsigned base = waveid * REG;
    for (int i = tid; i < 1024; i += 256) h[i] = 0u;
    __syncthreads();

    float ps = 0.0f;
    unsigned kmax = 0u, cur = 0u, ovf = 0u;
    const int n4 = n >> 2;
    const float4* x4 = (const float4*)x;
    const float4* y4 = (const float4*)y;
    const unsigned gtid = blockIdx.x * blockDim.x + tid;
    const unsigned gstride = gridDim.x * blockDim.x;
    for (unsigned i = gtid; i < (unsigned)n4; i += gstride) {
        float4 xv = x4[i];
        float4 yv = y4[i];
        float xs[4] = {xv.x, xv.y, xv.z, xv.w};
        float ys[4] = {yv.x, yv.y, yv.z, yv.w};
#pragma unroll
        for (int c = 0; c < 4; ++c) {
            bool pos = ys[c] > 0.0f;
            if (pos) ps += softplusf(-xs[c]);
            unsigned k = f2key(xs[c]);
            bool cnd = (!pos) && (k >= K0);
            unsigned long long mask = __ballot(cnd);
            if (mask) {
                if (cnd) {
                    kmax = max(kmax, k);
                    unsigned b = fl1(k - K0); if (b > 1023u) b = 1023u;
                    atomicAdd(&h[b], 1u);
                    unsigned slot = cur + (unsigned)__popcll(mask & ((1ull << lane) - 1ull));
                    unsigned gi = base + slot;
                    if (slot < REG && gi < cap_words) cand[gi] = k;
                    else ovf = 1u;
                }
                cur += (unsigned)__popcll(mask);
            }
        }
    }
    // tail (n % 4): wave 0, all lanes (keeps cur uniform)
    if (waveid == 0) {
        for (int i = (n & ~3) + lane; i < n; i += 64) {
            float xs = x[i];
            bool pos = y[i] > 0.0f;
            if (pos) ps += softplusf(-xs);
            unsigned k = f2key(xs);
            bool cnd = (!pos) && (k >= K0);
            unsigned long long mask = __ballot(cnd);
            if (mask) {
                if (cnd) {
                    kmax = max(kmax, k);
                    unsigned b = fl1(k - K0); if (b > 1023u) b = 1023u;
                    atomicAdd(&h[b], 1u);
                    unsigned slot = cur + (unsigned)__popcll(mask & ((1ull << lane) - 1ull));
                    unsigned gi = base + slot;
                    if (slot < REG && gi < cap_words) cand[gi] = k;
                    else ovf = 1u;
                }
                cur += (unsigned)__popcll(mask);
            }
        }
    }
    // zero-fill padding (stage phases skip k < K0; 0 < K0)
    for (unsigned j = cur + lane; j < REG; j += 64) {
        unsigned gi = base + j;
        if (gi < cap_words) cand[gi] = 0u;
    }
    if (base + REG > cap_words) ovf = 1u;     // region didn't fit
    ps = wred(ps);
    kmax = wredmax(kmax);
    unsigned anyovf = (__ballot(ovf != 0u) != 0ull) ? 0x80000000u : 0u;
    if (lane == 0) {
        ws[OFF_CNT + waveid] = (cur & 0x7FFFFFFFu) | anyovf;
        ((float*)ws)[OFF_POSP + waveid] = ps;
        ws[OFF_MAXK + waveid] = kmax;
    }
    // merge LDS hist into partial (blockIdx % NPART); only nonzero bins
    __syncthreads();
    unsigned* part = ws + OFF_H1P + (blockIdx.x & (NPART - 1)) * 1024;
    for (int i = tid; i < 1024; i += 256)
        if (h[i]) atomicAdd(&part[i], h[i]);
}

// ---- k_B: slot-reduce + scan1 + ONE cand stream (sure-sum + compact) ----
__global__ __launch_bounds__(BT)
void k_B(unsigned* __restrict__ ws, const int* __restrict__ pos_num) {
    const int t = threadIdx.x;
    const unsigned Kneg = (unsigned)(pos_num[0] * 3);

    unsigned tot = 0u, mk = 0u, ov = 0u;
    float psum = 0.0f;
    for (unsigned i = t; i < NWAVES; i += BT) {
        unsigned cc = ws[OFF_CNT + i];
        tot += cc & 0x7FFFFFFFu;
        ov |= cc >> 31;
        mk = max(mk, ws[OFF_MAXK + i]);
        psum += ((float*)ws)[OFF_POSP + i];
    }
    blockreduce4(tot, mk, ov, psum);
    const bool hard = (tot < Kneg) || (mk >= FINE_LIMIT) || (ov != 0u);
    if (blockIdx.x == 0 && t == 0) {
        Ctrl* c = (Ctrl*)ws;
        c->pos_sum = psum; c->cand_count = tot; c->maxkey = mk; c->hard = hard ? 1u : 0u;
    }
    if (hard) return;                       // k_C takes the slow path

    unsigned b1, r1;
    scan_desc<BT>(ws + OFF_H1P, NPART, 1024, 1024, Kneg, &b1, &r1);

    const unsigned wv = blockIdx.x * (BT / 64) + (unsigned)(t >> 6);
    const unsigned lane = (unsigned)(t & 63);
    unsigned cur2 = 0u;
    float ssv = 0.0f;
    const uint4* c4 = (const uint4*)(ws + OFF_CAND);
    for (unsigned i = blockIdx.x * BT + t; i < (unsigned)(CANDW / 4); i += BBLK * BT) {
        uint4 v = c4[i];
        unsigned ks[4] = {v.x, v.y, v.z, v.w};
#pragma unroll
        for (int cc = 0; cc < 4; ++cc) {
            unsigned k = ks[cc];
            bool ge = (k >= K0);
            unsigned b = ge ? fl1(k - K0) : 0u;
            if (ge && b > b1) ssv += softplusf(key2f(k));
            bool hit = ge && (b == b1);
            unsigned long long m = __ballot(hit);
            if (m) {
                if (hit) {
                    unsigned slot = cur2 + (unsigned)__popcll(m & ((1ull << lane) - 1ull));
                    if (slot < (unsigned)REG2) ws[OFF_CAND2 + wv * REG2 + slot] = k;
                }
                cur2 += (unsigned)__popcll(m);
            }
        }
    }
    if (lane == 0) {
        ws[OFF_CNT2 + wv] = cur2 < (unsigned)REG2 ? cur2 : (unsigned)REG2;
        if (cur2 > (unsigned)REG2) ws[OFF_FLG] = 1u;   // benign same-value race
    }
    ssv = bred(ssv);
    if (t == 0) ((float*)ws)[OFF_SS + blockIdx.x] = ssv;
    // b1/r1 recomputed redundantly by k_C's scan? No: k_C needs them -> store.
    if (blockIdx.x == 0 && t == 0) { ws[16] = b1; ws[17] = r1; }
}

// ---- correct single-block fallback: coarse 3-level select from x,y ----
// Never taken for the bench input. Block 0 of k_C only.
__device__ void slow_select(const float* __restrict__ x, const float* __restrict__ y,
                            unsigned* __restrict__ ws, int n, unsigned Kneg, int pos,
                            float* __restrict__ out,
                            unsigned* ha /*>=4096*/, unsigned* hb /*>=2048*/) {
    Ctrl* c = (Ctrl*)ws;
    const int t = threadIdx.x;
    __shared__ unsigned bc[2];
    // L1 coarse
    if (t < 1024) ha[t] = 0u;
    __syncthreads();
    for (int i = t; i < n; i += SELT)
        if (y[i] == 0.0f) atomicAdd(&ha[hl1(f2key(x[i]))], 1u);
    __syncthreads();
    if (t == 0) {
        unsigned cum = 0, b = 0, r = 1;
        for (int bin = 1023; bin >= 0; --bin) {
            unsigned v = ha[bin];
            if (cum + v >= Kneg) { b = (unsigned)bin; r = Kneg - cum; break; }
            cum += v;
        }
        bc[0] = b; bc[1] = r;
    }
    __syncthreads();
    const unsigned b1 = bc[0], r1 = bc[1];
    __syncthreads();
    // L2
    for (int i = t; i < 4096; i += SELT) ha[i] = 0u;
    __syncthreads();
    float ss = 0.0f;
    for (int i = t; i < n; i += SELT)
        if (y[i] == 0.0f) {
            unsigned k = f2key(x[i]);
            unsigned b = hl1(k);
            if (b > b1) ss += softplusf(key2f(k));
            else if (b == b1) atomicAdd(&ha[hl2(k)], 1u);
        }
    __syncthreads();
    if (t == 0) {
        unsigned cum = 0, b = 0, r = 1;
        for (int bin = 4095; bin >= 0; --bin) {
            unsigned v = ha[bin];
            if (cum + v >= r1) { b = (unsigned)bin; r = r1 - cum; break; }
            cum += v;
        }
        bc[0] = b; bc[1] = r;
    }
    __syncthreads();
    const unsigned b2 = bc[0], r2 = bc[1];
    // L3
    unsigned* h3c = hb;
    float* h3f = (float*)(hb + 1024);
    if (t < 1024) { h3c[t] = 0u; h3f[t] = 0.0f; }
    __syncthreads();
    float s2 = 0.0f;
    for (int i = t; i < n; i += SELT)
        if (y[i] == 0.0f) {
            unsigned k = f2key(x[i]);
            if (hl1(k) == b1) {
                unsigned l2 = hl2(k);
                if (l2 > b2) s2 += softplusf(key2f(k));
                else if (l2 == b2) {
                    atomicAdd(&h3c[hl3(k)], 1u);
                    atomicAdd(&h3f[hl3(k)], softplusf(key2f(k)));
                }
            }
        }
    __syncthreads();
    ss = bred(ss);
    s2 = bred(s2);
    if (t == 0) {
        unsigned cum = 0, c3 = 0, r3 = 1;
        for (int bin = 1023; bin >= 0; --bin) {
            unsigned v = h3c[bin];
            if (cum + v >= r2) { c3 = (unsigned)bin; r3 = r2 - cum; break; }
            cum += v;
        }
        float sf = 0.0f;
        for (int j = (int)c3 + 1; j < 1024; ++j) sf += h3f[j];
        unsigned H = (b1 << 22) | (b2 << 10) | c3;
        out[0] = (c->pos_sum + ss + s2 + sf + (float)r3 * softplusf(key2f(H)))
                 / (float)(4 * pos);
    }
}

// ---- k_C: hist2/hist3 from compacted keys; final combine ----
__global__ __launch_bounds__(SELT)
void k_C(const float* __restrict__ x, const float* __restrict__ y,
         unsigned* __restrict__ ws, const int* __restrict__ pos_num,
         int n, float* __restrict__ out) {
    __shared__ unsigned smA[4096];     // hist2; slow: h1/h2
    __shared__ unsigned slowbuf[2048]; // slow: h3c+h3f
    __shared__ unsigned h3c[16];
    __shared__ float    h3f[16];
    Ctrl* c = (Ctrl*)ws;
    const int t = threadIdx.x;
    const int pos = pos_num[0];
    const unsigned Kneg = (unsigned)(pos * 3);
    const bool slow = (c->hard != 0u) || (ws[OFF_FLG] != 0u);
    if (slow) {
        slow_select(x, y, ws, n, Kneg, pos, out, smA, slowbuf);
        return;
    }
    const unsigned b1 = ws[16], r1 = ws[17];
    // hist2 over b1-keys read from per-wave global regions (thread t = region t)
    for (int i = t; i < 4096; i += SELT) smA[i] = 0u;
    __syncthreads();
    const unsigned cnt = ws[OFF_CNT2 + t];           // already clamped <= REG2
    const unsigned rbase = OFF_CAND2 + (unsigned)t * REG2;
    for (unsigned j = 0; j < cnt; ++j)
        atomicAdd(&smA[fl2(ws[rbase + j] - K0)], 1u);
    __syncthreads();
    unsigned b2, r2;
    scan_desc<SELT>(smA, 1, 0, 4096, r1, &b2, &r2);
    if (t < 16) { h3c[t] = 0u; h3f[t] = 0.0f; }
    __syncthreads();
    float s2 = 0.0f;
    for (unsigned j = 0; j < cnt; ++j) {
        unsigned k = ws[rbase + j];
        unsigned l2 = fl2(k - K0);
        if (l2 > b2) s2 += softplusf(key2f(k));
        else if (l2 == b2) {
            atomicAdd(&h3c[fl3(k - K0)], 1u);
            atomicAdd(&h3f[fl3(k - K0)], softplusf(key2f(k)));
        }
    }
    __syncthreads();
    s2 = bred(s2);
    if (t == 0) {
        unsigned cum = 0, c3 = 0, r3 = 1;
        for (int bin = 15; bin >= 0; --bin) {
            unsigned v = h3c[bin];
            if (cum + v >= r2) { c3 = (unsigned)bin; r3 = r2 - cum; break; }
            cum += v;
        }
        float sf = 0.0f;
        for (int j = (int)c3 + 1; j < 16; ++j) sf += h3f[j];
        float ssT = 0.0f;
        for (int i = 0; i < BBLK; ++i) ssT += ((float*)ws)[OFF_SS + i];
        unsigned H = K0 + ((b1 << 16) | (b2 << 4) | c3);
        out[0] = (c->pos_sum + ssT + s2 + sf + (float)r3 * softplusf(key2f(H)))
                 / (float)(4 * pos);
    }
}

extern "C" void kernel_launch(void* const* d_in, const int* in_sizes, int n_in,
                              void* d_out, int out_size, void* d_ws, size_t ws_size,
                              hipStream_t stream) {
    const float* x = (const float*)d_in[0];
    const float* y = (const float*)d_in[1];
    const int* pos_num = (const int*)d_in[2];
    float* out = (float*)d_out;
    const int n = in_sizes[0];

    unsigned* ws = (unsigned*)d_ws;
    unsigned cap_words = 0u;
    if (ws_size / 4 > (size_t)OFF_CAND)
        cap_words = (unsigned)(ws_size / 4 - OFF_CAND);
    if (cap_words > (unsigned)CANDW) cap_words = (unsigned)CANDW;

    hipMemsetAsync(d_ws, 0, ZERO_BYTES, stream);   // CTRL + L1 partials
    k_main<<<2048, 256, 0, stream>>>(x, y, ws, cap_words, n);
    k_B<<<BBLK, BT, 0, stream>>>(ws, pos_num);
    k_C<<<1, SELT, 0, stream>>>(x, y, ws, pos_num, n, out);
}